// Round 12
// baseline (328.334 us; speedup 1.0000x reference)
//
#include <hip/hip_runtime.h>

#define NN 100000
#define NP 100096          // multiple of 64
#define EE 600000
#define GG 512
#define LN_EPS 1e-5f

typedef __attribute__((ext_vector_type(8))) __bf16 bf16x8;
typedef __attribute__((ext_vector_type(4))) float f32x4;

__device__ __forceinline__ unsigned short f2bf(float f) {
    unsigned int u = __float_as_uint(f);
    u = (u + 0x7fffu + ((u >> 16) & 1u)) >> 16;
    return (unsigned short)u;
}
__device__ __forceinline__ unsigned int pack2(float a, float b) {
    return (unsigned int)f2bf(a) | ((unsigned int)f2bf(b) << 16);
}
__device__ __forceinline__ void acc8(float* s, uint4 v) {
    s[0] += __uint_as_float(v.x << 16);
    s[1] += __uint_as_float(v.x & 0xffff0000u);
    s[2] += __uint_as_float(v.y << 16);
    s[3] += __uint_as_float(v.y & 0xffff0000u);
    s[4] += __uint_as_float(v.z << 16);
    s[5] += __uint_as_float(v.z & 0xffff0000u);
    s[6] += __uint_as_float(v.w << 16);
    s[7] += __uint_as_float(v.w & 0xffff0000u);
}

// ---------------- merged prep: assemble H0r + wtprep both layers + degree count ----------
#define PREP_A (NP * 10)
#define PREP_W0 (128 * 160)
#define PREP_W1 (128 * 256)
#define PREP_TOT (PREP_A + PREP_W0 + PREP_W1 + EE)

__global__ __launch_bounds__(256) void prep_kernel(
    const float* __restrict__ x, const float* __restrict__ xdims,
    const int* __restrict__ stt, const float* __restrict__ emb,
    const int* __restrict__ ei,
    const float* __restrict__ Wl0, const float* __restrict__ Wr0,
    const float* __restrict__ Wl1, const float* __restrict__ Wr1,
    unsigned short* __restrict__ H0r,
    unsigned short* __restrict__ Wt0, unsigned short* __restrict__ Wt1,
    int* __restrict__ deg)
{
    int idx = blockIdx.x * 256 + threadIdx.x;
    if (idx < PREP_A) {
        int node = idx / 10;
        int c8 = (idx - node * 10) * 8;   // feature base 0..72
        unsigned short vals[8];
        if (node < NN) {
            int st = stt[node];
            #pragma unroll
            for (int i = 0; i < 8; ++i) {
                int f = c8 + i;
                float v = 0.f;
                if (f < 60)      v = x[node * 60 + f];
                else if (f < 62) v = xdims[node * 2 + (f - 60)];
                else if (f < 74) v = emb[st * 12 + (f - 62)];
                vals[i] = f2bf(v);
            }
        } else {
            #pragma unroll
            for (int i = 0; i < 8; ++i) vals[i] = 0;
        }
        uint4 o;
        o.x = (unsigned)vals[0] | ((unsigned)vals[1] << 16);
        o.y = (unsigned)vals[2] | ((unsigned)vals[3] << 16);
        o.z = (unsigned)vals[4] | ((unsigned)vals[5] << 16);
        o.w = (unsigned)vals[6] | ((unsigned)vals[7] << 16);
        *(uint4*)(H0r + (size_t)node * 80 + c8) = o;
    } else if (idx < PREP_A + PREP_W0) {
        int j = idx - PREP_A;
        int n = j / 160, k = j - n * 160;
        float v = 0.f;
        if (k < 74)                  v = Wl0[k * 128 + n];
        else if (k >= 80 && k < 154) v = Wr0[(k - 80) * 128 + n];
        Wt0[(size_t)n * 160 + k] = f2bf(v);
    } else if (idx < PREP_A + PREP_W0 + PREP_W1) {
        int j = idx - PREP_A - PREP_W0;
        int n = j >> 8, k = j & 255;
        float v = (k < 128) ? Wl1[k * 128 + n] : Wr1[(k - 128) * 128 + n];
        Wt1[(size_t)n * 256 + k] = f2bf(v);
    } else if (idx < PREP_TOT) {
        int e = idx - PREP_A - PREP_W0 - PREP_W1;
        atomicAdd(&deg[ei[EE + e]], 1);
    }
}

// ---------------- exclusive scan of deg -> offs (local) + bsum ----------------
__global__ __launch_bounds__(256) void scan1_kernel(
    const int* __restrict__ deg, int* __restrict__ offs, int* __restrict__ bsum)
{
    __shared__ int ts[256];
    int t = threadIdx.x;
    int base = blockIdx.x * 2048 + t * 8;
    int d[8];
    if (base + 8 <= NN) {
        int4 a = *(const int4*)&deg[base];
        int4 b = *(const int4*)&deg[base + 4];
        d[0]=a.x; d[1]=a.y; d[2]=a.z; d[3]=a.w;
        d[4]=b.x; d[5]=b.y; d[6]=b.z; d[7]=b.w;
    } else {
        #pragma unroll
        for (int i = 0; i < 8; ++i) d[i] = (base + i < NN) ? deg[base + i] : 0;
    }
    int e[8]; int run = 0;
    #pragma unroll
    for (int i = 0; i < 8; ++i) { e[i] = run; run += d[i]; }
    ts[t] = run;
    int tot = run;
    __syncthreads();
    for (int off = 1; off < 256; off <<= 1) {
        int u = (t >= off) ? ts[t - off] : 0;
        __syncthreads();
        ts[t] += u;
        __syncthreads();
    }
    int pre = ts[t] - tot;
    #pragma unroll
    for (int i = 0; i < 8; ++i) if (base + i < NN) offs[base + i] = e[i] + pre;
    if (t == 255) bsum[blockIdx.x] = ts[255];
}

__global__ void scan2_kernel(int* __restrict__ bsum, int nb)
{
    int t = threadIdx.x;   // one wave
    int v = (t < nb) ? bsum[t] : 0;
    int inc = v;
    for (int off = 1; off < 64; off <<= 1) {
        int u = __shfl_up(inc, off, 64);
        if (t >= off) inc += u;
    }
    if (t < nb) bsum[t] = inc - v;   // exclusive
}

// ---------------- CSR fill (bsum folded in) ----------------
__global__ __launch_bounds__(256) void fill_csr_kernel(
    const int* __restrict__ ei, int* __restrict__ cur,
    const int* __restrict__ offs, const int* __restrict__ bsum,
    int* __restrict__ csr)
{
    int e = blockIdx.x * 256 + threadIdx.x;
    if (e >= EE) return;
    int d = ei[EE + e];
    int p = offs[d] + bsum[d >> 11] + atomicAdd(&cur[d], 1);
    csr[p] = ei[e];
}

// ---------------- agg0: gather H0r -> mean into A0g (dense 80-col rows) ----------------
__global__ __launch_bounds__(256) void agg0_kernel(
    const unsigned short* __restrict__ H0r, unsigned short* __restrict__ A0g,
    const int* __restrict__ csr, const int* __restrict__ offs,
    const int* __restrict__ bsum, const int* __restrict__ deg)
{
    int node = blockIdx.x * 16 + (threadIdx.x >> 4);
    int lane = threadIdx.x & 15;
    if (node >= NP || lane >= 10) return;
    int d = 0, st = 0;
    if (node < NN) { d = deg[node]; st = offs[node] + bsum[node >> 11]; }
    float iv = 1.0f / (float)(d > 1 ? d : 1);
    float s[8];
    #pragma unroll
    for (int i = 0; i < 8; ++i) s[i] = 0.f;
    int e = 0;
    for (; e + 4 <= d; e += 4) {
        int i0 = csr[st + e],     i1 = csr[st + e + 1];
        int i2 = csr[st + e + 2], i3 = csr[st + e + 3];
        uint4 v0 = *(const uint4*)(H0r + (size_t)i0 * 80 + lane * 8);
        uint4 v1 = *(const uint4*)(H0r + (size_t)i1 * 80 + lane * 8);
        uint4 v2 = *(const uint4*)(H0r + (size_t)i2 * 80 + lane * 8);
        uint4 v3 = *(const uint4*)(H0r + (size_t)i3 * 80 + lane * 8);
        acc8(s, v0); acc8(s, v1); acc8(s, v2); acc8(s, v3);
    }
    for (; e < d; ++e) {
        int i0 = csr[st + e];
        uint4 v0 = *(const uint4*)(H0r + (size_t)i0 * 80 + lane * 8);
        acc8(s, v0);
    }
    uint4 o;
    o.x = pack2(s[0] * iv, s[1] * iv);
    o.y = pack2(s[2] * iv, s[3] * iv);
    o.z = pack2(s[4] * iv, s[5] * iv);
    o.w = pack2(s[6] * iv, s[7] * iv);
    *(uint4*)(A0g + (size_t)node * 80 + lane * 8) = o;
}

// ---------------- agg1: gather H1 -> mean into A1g (dense 128-col rows) ----------------
__global__ __launch_bounds__(256) void agg1_kernel(
    const unsigned short* __restrict__ H1, unsigned short* __restrict__ A1g,
    const int* __restrict__ csr, const int* __restrict__ offs,
    const int* __restrict__ bsum, const int* __restrict__ deg)
{
    int node = blockIdx.x * 16 + (threadIdx.x >> 4);
    int lane = threadIdx.x & 15;
    if (node >= NP) return;
    int d = 0, st = 0;
    if (node < NN) { d = deg[node]; st = offs[node] + bsum[node >> 11]; }
    float iv = 1.0f / (float)(d > 1 ? d : 1);
    float s[8];
    #pragma unroll
    for (int i = 0; i < 8; ++i) s[i] = 0.f;
    int e = 0;
    for (; e + 4 <= d; e += 4) {
        int i0 = csr[st + e],     i1 = csr[st + e + 1];
        int i2 = csr[st + e + 2], i3 = csr[st + e + 3];
        uint4 v0 = *(const uint4*)(H1 + (size_t)i0 * 128 + lane * 8);
        uint4 v1 = *(const uint4*)(H1 + (size_t)i1 * 128 + lane * 8);
        uint4 v2 = *(const uint4*)(H1 + (size_t)i2 * 128 + lane * 8);
        uint4 v3 = *(const uint4*)(H1 + (size_t)i3 * 128 + lane * 8);
        acc8(s, v0); acc8(s, v1); acc8(s, v2); acc8(s, v3);
    }
    for (; e < d; ++e) {
        int i0 = csr[st + e];
        uint4 v0 = *(const uint4*)(H1 + (size_t)i0 * 128 + lane * 8);
        acc8(s, v0);
    }
    uint4 o;
    o.x = pack2(s[0] * iv, s[1] * iv);
    o.y = pack2(s[2] * iv, s[3] * iv);
    o.z = pack2(s[4] * iv, s[5] * iv);
    o.w = pack2(s[6] * iv, s[7] * iv);
    *(uint4*)(A1g + (size_t)node * 128 + lane * 8) = o;
}

// ---------------- GEMM: two 32-node tiles per block, double-buffered pipeline ---------
// block = 256 thr = 4 waves; per tile: 32 nodes x 128 cols (R10's exact compute).
// Pipeline: stage t0 (VGPR->LDS) ; ISSUE t1 global loads ; barrier ;
//           compute t0 (kt-outer) ; write t1 VGPRs->LDS (waitcnt lands here,
//           covered by compute t0) ; barrier ; compute t1 ; epilogues.
// A staged with stride AS=K+8 shorts (2-way bank alias only).
// A-frag per m120 (node=lane&15, k=(lane>>4)*8+j); C/D per m89.
template<int K, bool POOL>
__global__ __launch_bounds__(256, 4) void gemm_kernel(
    const unsigned short* __restrict__ Ag,
    const unsigned short* __restrict__ Hr,
    const unsigned short* __restrict__ Wt,
    const float* __restrict__ bias, const float* __restrict__ gamma,
    const float* __restrict__ beta,
    unsigned short* __restrict__ outH,            // !POOL: H1 (dense 128)
    const int* __restrict__ batch,                // POOL only
    float* __restrict__ psum, int* __restrict__ pmax)
{
    constexpr int KT = K / 32, AS = K + 8, CPR = K / 8, CPRh = CPR / 2, KH = K / 2;
    constexpr int BUF = 32 * AS;                       // shorts per tile buffer
    constexpr int NPRE = (32 * CPR + 255) / 256;       // prefetch chunks per thread
    constexpr int ASMB = 2 * BUF * 2;                  // bytes, both buffers
    constexpr int SMEM = (!POOL || ASMB > 64 * 128 * 4) ? ASMB : 64 * 128 * 4;
    __shared__ __align__(16) char smem[SMEM];
    unsigned short* A0s = (unsigned short*)smem;       // tile0
    unsigned short* A1s = A0s + BUF;                   // tile1
    float* Hs = (float*)smem;                          // POOL: aliases both (post-compute)
    __shared__ __align__(16) float sP[64 * 4];
    __shared__ __align__(16) float qP[64 * 4];
    __shared__ int bS[POOL ? 64 : 1];

    const int tid = threadIdx.x;
    const int n0 = blockIdx.x * 64;

    if (POOL && tid < 64) {
        int gn = n0 + tid;
        bS[tid] = (gn < NN) ? batch[gn] : -1;
    }
    // stage tile0 -> A0s (R10's exact staging)
    for (int i = tid; i < 32 * CPR; i += 256) {
        int node = i / CPR, c = i - node * CPR;
        size_t gn = (size_t)(n0 + node);
        const unsigned short* src = (c < CPRh)
            ? (Ag + gn * KH + c * 8)
            : (Hr + gn * KH + (c - CPRh) * 8);
        *(uint4*)(A0s + node * AS + c * 8) = *(const uint4*)src;
    }
    // issue tile1 global loads (latency covered by barrier + compute t0)
    uint4 pre[NPRE];
    #pragma unroll
    for (int p = 0; p < NPRE; ++p) {
        int i = tid + p * 256;
        if (i < 32 * CPR) {
            int node = i / CPR, c = i - node * CPR;
            size_t gn = (size_t)(n0 + 32 + node);
            const unsigned short* src = (c < CPRh)
                ? (Ag + gn * KH + c * 8)
                : (Hr + gn * KH + (c - CPRh) * 8);
            pre[p] = *(const uint4*)src;
        }
    }

    const int l = tid & 63, w = tid >> 6;
    const int g = l >> 4, c0 = l & 15;
    float bia[2], gam[2], bet[2];
    #pragma unroll
    for (int j = 0; j < 2; ++j) {
        int col = (2 * w + j) * 16 + c0;
        bia[j] = bias[col]; gam[j] = gamma[col]; bet[j] = beta[col];
    }
    const unsigned short* bp0 = Wt + (size_t)((2 * w + 0) * 16 + c0) * K + g * 8;
    const unsigned short* bp1 = Wt + (size_t)((2 * w + 1) * 16 + c0) * K + g * 8;
    __syncthreads();   // tile0 staged

    f32x4 acc[2][2][2];  // [tile][m][j]
    #pragma unroll
    for (int t = 0; t < 2; ++t)
        #pragma unroll
        for (int m = 0; m < 2; ++m) {
            acc[t][m][0] = (f32x4){0.f,0.f,0.f,0.f};
            acc[t][m][1] = (f32x4){0.f,0.f,0.f,0.f};
        }

    // compute tile0 (identical to R10's K-loop)
    {
        const unsigned short* ar0 = A0s + (0 * 16 + c0) * AS + g * 8;
        const unsigned short* ar1 = A0s + (1 * 16 + c0) * AS + g * 8;
        #pragma unroll
        for (int kt = 0; kt < KT; ++kt) {
            bf16x8 b0 = *(const bf16x8*)(bp0 + kt * 32);
            bf16x8 b1 = *(const bf16x8*)(bp1 + kt * 32);
            bf16x8 a0 = *(const bf16x8*)(ar0 + kt * 32);
            bf16x8 a1 = *(const bf16x8*)(ar1 + kt * 32);
            acc[0][0][0] = __builtin_amdgcn_mfma_f32_16x16x32_bf16(a0, b0, acc[0][0][0], 0, 0, 0);
            acc[0][0][1] = __builtin_amdgcn_mfma_f32_16x16x32_bf16(a0, b1, acc[0][0][1], 0, 0, 0);
            acc[0][1][0] = __builtin_amdgcn_mfma_f32_16x16x32_bf16(a1, b0, acc[0][1][0], 0, 0, 0);
            acc[0][1][1] = __builtin_amdgcn_mfma_f32_16x16x32_bf16(a1, b1, acc[0][1][1], 0, 0, 0);
        }
    }
    // write tile1 prefetch -> A1s (waitcnt here, after compute t0)
    #pragma unroll
    for (int p = 0; p < NPRE; ++p) {
        int i = tid + p * 256;
        if (i < 32 * CPR) {
            int node = i / CPR, c = i - node * CPR;
            *(uint4*)(A1s + node * AS + c * 8) = pre[p];
        }
    }
    __syncthreads();   // tile1 staged
    // compute tile1
    {
        const unsigned short* ar0 = A1s + (0 * 16 + c0) * AS + g * 8;
        const unsigned short* ar1 = A1s + (1 * 16 + c0) * AS + g * 8;
        #pragma unroll
        for (int kt = 0; kt < KT; ++kt) {
            bf16x8 b0 = *(const bf16x8*)(bp0 + kt * 32);
            bf16x8 b1 = *(const bf16x8*)(bp1 + kt * 32);
            bf16x8 a0 = *(const bf16x8*)(ar0 + kt * 32);
            bf16x8 a1 = *(const bf16x8*)(ar1 + kt * 32);
            acc[1][0][0] = __builtin_amdgcn_mfma_f32_16x16x32_bf16(a0, b0, acc[1][0][0], 0, 0, 0);
            acc[1][0][1] = __builtin_amdgcn_mfma_f32_16x16x32_bf16(a0, b1, acc[1][0][1], 0, 0, 0);
            acc[1][1][0] = __builtin_amdgcn_mfma_f32_16x16x32_bf16(a1, b0, acc[1][1][0], 0, 0, 0);
            acc[1][1][1] = __builtin_amdgcn_mfma_f32_16x16x32_bf16(a1, b1, acc[1][1][1], 0, 0, 0);
        }
    }

    // LN phase 1: per-wave partials, both tiles (node 0..63)
    #pragma unroll
    for (int t = 0; t < 2; ++t) {
        #pragma unroll
        for (int m = 0; m < 2; ++m) {
            #pragma unroll
            for (int r = 0; r < 4; ++r) {
                float h0v = acc[t][m][0][r] + bia[0];
                float h1v = acc[t][m][1][r] + bia[1];
                float s = h0v + h1v, q = h0v * h0v + h1v * h1v;
                #pragma unroll
                for (int mm = 1; mm < 16; mm <<= 1) {
                    s += __shfl_xor(s, mm, 64);
                    q += __shfl_xor(q, mm, 64);
                }
                if (c0 == 0) {
                    int node = t * 32 + m * 16 + g * 4 + r;
                    sP[node * 4 + w] = s;
                    qP[node * 4 + w] = q;
                }
            }
        }
    }
    __syncthreads();   // MFMA LDS reads done; sP/qP visible

    // LN phase 2 + ReLU + store
    #pragma unroll
    for (int t = 0; t < 2; ++t) {
        #pragma unroll
        for (int m = 0; m < 2; ++m) {
            #pragma unroll
            for (int r = 0; r < 4; ++r) {
                int node = t * 32 + m * 16 + g * 4 + r;
                float4 sv = *(const float4*)&sP[node * 4];
                float4 qv = *(const float4*)&qP[node * 4];
                float s = (sv.x + sv.y) + (sv.z + sv.w);
                float q = (qv.x + qv.y) + (qv.z + qv.w);
                float mu   = s * (1.f / 128.f);
                float var  = q * (1.f / 128.f) - mu * mu;
                float rinv = rsqrtf(var + LN_EPS);
                float h0v = acc[t][m][0][r] + bia[0];
                float h1v = acc[t][m][1][r] + bia[1];
                float v0 = fmaxf(0.f, (h0v - mu) * rinv * gam[0] + bet[0]);
                float v1 = fmaxf(0.f, (h1v - mu) * rinv * gam[1] + bet[1]);
                if (POOL) {
                    Hs[node * 128 + (2 * w) * 16 + c0]     = v0;
                    Hs[node * 128 + (2 * w + 1) * 16 + c0] = v1;
                } else {
                    size_t gn = (size_t)(n0 + node);
                    outH[gn * 128 + (2 * w) * 16 + c0]     = f2bf(v0);
                    outH[gn * 128 + (2 * w + 1) * 16 + c0] = f2bf(v1);
                }
            }
        }
    }
    if (!POOL) return;
    __syncthreads();

    // fused pooling: 128 threads, one column each; sorted batch -> few flushes
    if (tid < 128) {
        int j = tid;
        int curg = -1; float s = 0.f, m = 0.f;
        #pragma unroll 4
        for (int n = 0; n < 64; ++n) {
            int gb = bS[n];
            if (gb < 0) break;
            if (gb != curg) {
                if (curg >= 0) {
                    atomicAdd(&psum[curg * 128 + j], s);
                    atomicMax(&pmax[curg * 128 + j], __float_as_int(m));
                }
                curg = gb; s = 0.f; m = 0.f;
            }
            float v = Hs[n * 128 + j];
            s += v; m = fmaxf(m, v);
        }
        if (curg >= 0) {
            atomicAdd(&psum[curg * 128 + j], s);
            atomicMax(&pmax[curg * 128 + j], __float_as_int(m));
        }
    }
}

// ---------------- final MLP (one block per graph; cnt via binary search) ----------------
__device__ __forceinline__ int lbound(const int* a, int n, int v) {
    int lo = 0, hi = n;
    while (lo < hi) { int mid = (lo + hi) >> 1; if (a[mid] < v) lo = mid + 1; else hi = mid; }
    return lo;
}

__global__ __launch_bounds__(64) void mlp_kernel(
    const float* __restrict__ psum, const int* __restrict__ pmax,
    const int* __restrict__ batch,
    const float* __restrict__ Wf0, const float* __restrict__ bf0,
    const float* __restrict__ Wf1, const float* __restrict__ bf1,
    const float* __restrict__ Wf2, const float* __restrict__ bf2,
    float* __restrict__ out)
{
    __shared__ float z[256];
    __shared__ float t1[50];
    __shared__ float t2[50];
    __shared__ int cS;
    int g = blockIdx.x, t = threadIdx.x;
    if (t == 0) cS = lbound(batch, NN, g + 1) - lbound(batch, NN, g);
    __syncthreads();
    int c = cS;
    float ic = 1.0f / (float)(c > 1 ? c : 1);
    for (int j = t; j < 128; j += 64) {
        z[j]       = psum[g * 128 + j] * ic;
        z[128 + j] = __int_as_float(pmax[g * 128 + j]);
    }
    __syncthreads();
    if (t < 50) {
        float a = bf0[t];
        for (int k = 0; k < 256; ++k) a = fmaf(z[k], Wf0[k * 50 + t], a);
        t1[t] = fmaxf(a, 0.0f);
    }
    __syncthreads();
    if (t < 50) {
        float a = bf1[t];
        for (int k = 0; k < 50; ++k) a = fmaf(t1[k], Wf1[k * 50 + t], a);
        t2[t] = fmaxf(a, 0.0f);
    }
    __syncthreads();
    if (t < 10) {
        float a = bf2[t];
        for (int k = 0; k < 50; ++k) a = fmaf(t2[k], Wf2[k * 10 + t], a);
        out[g * 10 + t] = fmaxf(a, 0.0f);
    }
}

// ---------------- launcher ----------------
extern "C" void kernel_launch(void* const* d_in, const int* in_sizes, int n_in,
                              void* d_out, int out_size, void* d_ws, size_t ws_size,
                              hipStream_t stream)
{
    const float* x     = (const float*)d_in[0];
    const float* xdims = (const float*)d_in[1];
    const int*   stt   = (const int*)d_in[2];
    const int*   ei    = (const int*)d_in[3];
    const int*   batch = (const int*)d_in[4];
    const float* emb   = (const float*)d_in[5];
    const float* Wl0   = (const float*)d_in[6];
    const float* bl0   = (const float*)d_in[7];
    const float* Wr0   = (const float*)d_in[8];
    const float* g0    = (const float*)d_in[9];
    const float* bn0   = (const float*)d_in[10];
    const float* Wl1   = (const float*)d_in[11];
    const float* bl1   = (const float*)d_in[12];
    const float* Wr1   = (const float*)d_in[13];
    const float* g1    = (const float*)d_in[14];
    const float* bn1   = (const float*)d_in[15];
    const float* Wf0   = (const float*)d_in[16];
    const float* bf0   = (const float*)d_in[17];
    const float* Wf1   = (const float*)d_in[18];
    const float* bf1   = (const float*)d_in[19];
    const float* Wf2   = (const float*)d_in[20];
    const float* bf2   = (const float*)d_in[21];

    char* w = (char*)d_ws;
    unsigned short* H0r = (unsigned short*)w; w += (size_t)NP * 80 * 2;
    unsigned short* A0g = (unsigned short*)w; w += (size_t)NP * 80 * 2;
    unsigned short* H1  = (unsigned short*)w; w += (size_t)NP * 128 * 2;
    unsigned short* A1g = (unsigned short*)w; w += (size_t)NP * 128 * 2;
    unsigned short* Wt0 = (unsigned short*)w; w += (size_t)128 * 160 * 2;
    unsigned short* Wt1 = (unsigned short*)w; w += (size_t)128 * 256 * 2;
    int*   csr    = (int*)w;   w += (size_t)EE * 4;
    int*   offs   = (int*)w;   w += (size_t)NN * 4;
    int*   bsum   = (int*)w;   w += 1024;
    // zeroed region (one memset):
    char* zbeg = w;
    int*   deg  = (int*)w;   w += (size_t)NP * 4;
    int*   cur  = (int*)w;   w += (size_t)NN * 4;
    float* psum = (float*)w; w += (size_t)GG * 128 * 4;
    int*   pmax = (int*)w;   w += (size_t)GG * 128 * 4;
    size_t zsz = (size_t)(w - zbeg);

    hipMemsetAsync(zbeg, 0, zsz, stream);

    prep_kernel<<<(PREP_TOT + 255) / 256, 256, 0, stream>>>(
        x, xdims, stt, emb, ei, Wl0, Wr0, Wl1, Wr1, H0r, Wt0, Wt1, deg);

    int nb = (NN + 2047) / 2048;   // 49
    scan1_kernel<<<nb, 256, 0, stream>>>(deg, offs, bsum);
    scan2_kernel<<<1, 64, 0, stream>>>(bsum, nb);
    fill_csr_kernel<<<(EE + 255) / 256, 256, 0, stream>>>(ei, cur, offs, bsum, csr);

    agg0_kernel<<<NP / 16, 256, 0, stream>>>(H0r, A0g, csr, offs, bsum, deg);
    gemm_kernel<160, false><<<NP / 64, 256, 0, stream>>>(
        A0g, H0r, Wt0, bl0, g0, bn0, H1, nullptr, nullptr, nullptr);
    agg1_kernel<<<NP / 16, 256, 0, stream>>>(H1, A1g, csr, offs, bsum, deg);
    gemm_kernel<256, true><<<NP / 64, 256, 0, stream>>>(
        A1g, H1, Wt1, bl1, g1, bn1, nullptr, batch, psum, pmax);

    mlp_kernel<<<GG, 64, 0, stream>>>(psum, pmax, batch, Wf0, bf0, Wf1, bf1, Wf2, bf2,
                                      (float*)d_out);
}

// Round 13
// 304.768 us; speedup vs baseline: 1.0773x; 1.0773x over previous
//
#include <hip/hip_runtime.h>

#define NN 100000
#define NP 100096          // multiple of 32/64
#define NT (NP / 32)       // 3128 gemm tiles
#define EE 600000
#define GG 512
#define LN_EPS 1e-5f

typedef __attribute__((ext_vector_type(8))) __bf16 bf16x8;
typedef __attribute__((ext_vector_type(4))) float f32x4;

__device__ __forceinline__ unsigned short f2bf(float f) {
    unsigned int u = __float_as_uint(f);
    u = (u + 0x7fffu + ((u >> 16) & 1u)) >> 16;
    return (unsigned short)u;
}
__device__ __forceinline__ unsigned int pack2(float a, float b) {
    return (unsigned int)f2bf(a) | ((unsigned int)f2bf(b) << 16);
}
__device__ __forceinline__ void acc8(float* s, uint4 v) {
    s[0] += __uint_as_float(v.x << 16);
    s[1] += __uint_as_float(v.x & 0xffff0000u);
    s[2] += __uint_as_float(v.y << 16);
    s[3] += __uint_as_float(v.y & 0xffff0000u);
    s[4] += __uint_as_float(v.z << 16);
    s[5] += __uint_as_float(v.z & 0xffff0000u);
    s[6] += __uint_as_float(v.w << 16);
    s[7] += __uint_as_float(v.w & 0xffff0000u);
}

// ---------------- merged prep: assemble H0r + wtprep both layers + degree count ----------
// All destination arrays are DENSE (full-line writes; no partial-line RMW).
#define PREP_A (NP * 10)
#define PREP_W0 (128 * 160)
#define PREP_W1 (128 * 256)
#define PREP_TOT (PREP_A + PREP_W0 + PREP_W1 + EE)

__global__ __launch_bounds__(256) void prep_kernel(
    const float* __restrict__ x, const float* __restrict__ xdims,
    const int* __restrict__ stt, const float* __restrict__ emb,
    const int* __restrict__ ei,
    const float* __restrict__ Wl0, const float* __restrict__ Wr0,
    const float* __restrict__ Wl1, const float* __restrict__ Wr1,
    unsigned short* __restrict__ H0r,
    unsigned short* __restrict__ Wt0, unsigned short* __restrict__ Wt1,
    int* __restrict__ deg)
{
    int idx = blockIdx.x * 256 + threadIdx.x;
    if (idx < PREP_A) {
        int node = idx / 10;
        int c8 = (idx - node * 10) * 8;   // feature base 0..72
        unsigned short vals[8];
        if (node < NN) {
            int st = stt[node];
            #pragma unroll
            for (int i = 0; i < 8; ++i) {
                int f = c8 + i;
                float v = 0.f;
                if (f < 60)      v = x[node * 60 + f];
                else if (f < 62) v = xdims[node * 2 + (f - 60)];
                else if (f < 74) v = emb[st * 12 + (f - 62)];
                vals[i] = f2bf(v);
            }
        } else {
            #pragma unroll
            for (int i = 0; i < 8; ++i) vals[i] = 0;
        }
        uint4 o;
        o.x = (unsigned)vals[0] | ((unsigned)vals[1] << 16);
        o.y = (unsigned)vals[2] | ((unsigned)vals[3] << 16);
        o.z = (unsigned)vals[4] | ((unsigned)vals[5] << 16);
        o.w = (unsigned)vals[6] | ((unsigned)vals[7] << 16);
        *(uint4*)(H0r + (size_t)node * 80 + c8) = o;
    } else if (idx < PREP_A + PREP_W0) {
        int j = idx - PREP_A;
        int n = j / 160, k = j - n * 160;
        float v = 0.f;
        if (k < 74)                  v = Wl0[k * 128 + n];
        else if (k >= 80 && k < 154) v = Wr0[(k - 80) * 128 + n];
        Wt0[(size_t)n * 160 + k] = f2bf(v);
    } else if (idx < PREP_A + PREP_W0 + PREP_W1) {
        int j = idx - PREP_A - PREP_W0;
        int n = j >> 8, k = j & 255;
        float v = (k < 128) ? Wl1[k * 128 + n] : Wr1[(k - 128) * 128 + n];
        Wt1[(size_t)n * 256 + k] = f2bf(v);
    } else if (idx < PREP_TOT) {
        int e = idx - PREP_A - PREP_W0 - PREP_W1;
        atomicAdd(&deg[ei[EE + e]], 1);
    }
}

// ---------------- exclusive scan of deg -> offs (local) + bsum ----------------
__global__ __launch_bounds__(256) void scan1_kernel(
    const int* __restrict__ deg, int* __restrict__ offs, int* __restrict__ bsum)
{
    __shared__ int ts[256];
    int t = threadIdx.x;
    int base = blockIdx.x * 2048 + t * 8;
    int d[8];
    if (base + 8 <= NN) {
        int4 a = *(const int4*)&deg[base];
        int4 b = *(const int4*)&deg[base + 4];
        d[0]=a.x; d[1]=a.y; d[2]=a.z; d[3]=a.w;
        d[4]=b.x; d[5]=b.y; d[6]=b.z; d[7]=b.w;
    } else {
        #pragma unroll
        for (int i = 0; i < 8; ++i) d[i] = (base + i < NN) ? deg[base + i] : 0;
    }
    int e[8]; int run = 0;
    #pragma unroll
    for (int i = 0; i < 8; ++i) { e[i] = run; run += d[i]; }
    ts[t] = run;
    int tot = run;
    __syncthreads();
    for (int off = 1; off < 256; off <<= 1) {
        int u = (t >= off) ? ts[t - off] : 0;
        __syncthreads();
        ts[t] += u;
        __syncthreads();
    }
    int pre = ts[t] - tot;
    #pragma unroll
    for (int i = 0; i < 8; ++i) if (base + i < NN) offs[base + i] = e[i] + pre;
    if (t == 255) bsum[blockIdx.x] = ts[255];
}

__global__ void scan2_kernel(int* __restrict__ bsum, int nb)
{
    int t = threadIdx.x;   // one wave
    int v = (t < nb) ? bsum[t] : 0;
    int inc = v;
    for (int off = 1; off < 64; off <<= 1) {
        int u = __shfl_up(inc, off, 64);
        if (t >= off) inc += u;
    }
    if (t < nb) bsum[t] = inc - v;   // exclusive
}

// ---------------- CSR fill (bsum folded in) ----------------
__global__ __launch_bounds__(256) void fill_csr_kernel(
    const int* __restrict__ ei, int* __restrict__ cur,
    const int* __restrict__ offs, const int* __restrict__ bsum,
    int* __restrict__ csr)
{
    int e = blockIdx.x * 256 + threadIdx.x;
    if (e >= EE) return;
    int d = ei[EE + e];
    int p = offs[d] + bsum[d >> 11] + atomicAdd(&cur[d], 1);
    csr[p] = ei[e];
}

// ---------------- agg0: gather H0r -> mean into A0g (dense 80-col rows) ----------------
__global__ __launch_bounds__(256) void agg0_kernel(
    const unsigned short* __restrict__ H0r, unsigned short* __restrict__ A0g,
    const int* __restrict__ csr, const int* __restrict__ offs,
    const int* __restrict__ bsum, const int* __restrict__ deg)
{
    int node = blockIdx.x * 16 + (threadIdx.x >> 4);
    int lane = threadIdx.x & 15;
    if (node >= NP || lane >= 10) return;
    int d = 0, st = 0;
    if (node < NN) { d = deg[node]; st = offs[node] + bsum[node >> 11]; }
    float iv = 1.0f / (float)(d > 1 ? d : 1);
    float s[8];
    #pragma unroll
    for (int i = 0; i < 8; ++i) s[i] = 0.f;
    int e = 0;
    for (; e + 4 <= d; e += 4) {
        int i0 = csr[st + e],     i1 = csr[st + e + 1];
        int i2 = csr[st + e + 2], i3 = csr[st + e + 3];
        uint4 v0 = *(const uint4*)(H0r + (size_t)i0 * 80 + lane * 8);
        uint4 v1 = *(const uint4*)(H0r + (size_t)i1 * 80 + lane * 8);
        uint4 v2 = *(const uint4*)(H0r + (size_t)i2 * 80 + lane * 8);
        uint4 v3 = *(const uint4*)(H0r + (size_t)i3 * 80 + lane * 8);
        acc8(s, v0); acc8(s, v1); acc8(s, v2); acc8(s, v3);
    }
    for (; e < d; ++e) {
        int i0 = csr[st + e];
        uint4 v0 = *(const uint4*)(H0r + (size_t)i0 * 80 + lane * 8);
        acc8(s, v0);
    }
    uint4 o;
    o.x = pack2(s[0] * iv, s[1] * iv);
    o.y = pack2(s[2] * iv, s[3] * iv);
    o.z = pack2(s[4] * iv, s[5] * iv);
    o.w = pack2(s[6] * iv, s[7] * iv);
    *(uint4*)(A0g + (size_t)node * 80 + lane * 8) = o;
}

// ---------------- agg1: gather H1 -> mean into A1g (dense 128-col rows) ----------------
__global__ __launch_bounds__(256) void agg1_kernel(
    const unsigned short* __restrict__ H1, unsigned short* __restrict__ A1g,
    const int* __restrict__ csr, const int* __restrict__ offs,
    const int* __restrict__ bsum, const int* __restrict__ deg)
{
    int node = blockIdx.x * 16 + (threadIdx.x >> 4);
    int lane = threadIdx.x & 15;
    if (node >= NP) return;
    int d = 0, st = 0;
    if (node < NN) { d = deg[node]; st = offs[node] + bsum[node >> 11]; }
    float iv = 1.0f / (float)(d > 1 ? d : 1);
    float s[8];
    #pragma unroll
    for (int i = 0; i < 8; ++i) s[i] = 0.f;
    int e = 0;
    for (; e + 4 <= d; e += 4) {
        int i0 = csr[st + e],     i1 = csr[st + e + 1];
        int i2 = csr[st + e + 2], i3 = csr[st + e + 3];
        uint4 v0 = *(const uint4*)(H1 + (size_t)i0 * 128 + lane * 8);
        uint4 v1 = *(const uint4*)(H1 + (size_t)i1 * 128 + lane * 8);
        uint4 v2 = *(const uint4*)(H1 + (size_t)i2 * 128 + lane * 8);
        uint4 v3 = *(const uint4*)(H1 + (size_t)i3 * 128 + lane * 8);
        acc8(s, v0); acc8(s, v1); acc8(s, v2); acc8(s, v3);
    }
    for (; e < d; ++e) {
        int i0 = csr[st + e];
        uint4 v0 = *(const uint4*)(H1 + (size_t)i0 * 128 + lane * 8);
        acc8(s, v0);
    }
    uint4 o;
    o.x = pack2(s[0] * iv, s[1] * iv);
    o.y = pack2(s[2] * iv, s[3] * iv);
    o.z = pack2(s[4] * iv, s[5] * iv);
    o.w = pack2(s[6] * iv, s[7] * iv);
    *(uint4*)(A1g + (size_t)node * 128 + lane * 8) = o;
}

// ---------------- GEMM (best measured: 32-node tile, LDS-staged A, kt-outer) ----------
// block = 256 thr = 4 waves; 32 nodes x 128 cols per block.
// Wave w covers cols [32w, 32w+32) (nt = 2w, 2w+1); m-tiles 0..1 (16 nodes each).
// A staged in LDS with stride AS=K+8 shorts (2-way bank alias only).
// kt-outer: 2 B global loads (L1/L2-hot) + 2 A ds_reads + 4 MFMA per kt.
// A-frag per m120 (node=lane&15, k=(lane>>4)*8+j); C/D per m89.
// NOTE (8-variant ledger, R5-R12): regB-resident, persistent, direct-global,
// async global_load_lds, 64-node, and 2-tile dbuf ALL regress vs this form.
template<int K, bool POOL>
__global__ __launch_bounds__(256, 4) void gemm_kernel(
    const unsigned short* __restrict__ Ag,
    const unsigned short* __restrict__ Hr,
    const unsigned short* __restrict__ Wt,
    const float* __restrict__ bias, const float* __restrict__ gamma,
    const float* __restrict__ beta,
    unsigned short* __restrict__ outH,            // !POOL: H1 (dense 128)
    const int* __restrict__ batch,                // POOL only
    float* __restrict__ psum, int* __restrict__ pmax)
{
    constexpr int KT = K / 32, AS = K + 8, CPR = K / 8, CPRh = CPR / 2, KH = K / 2;
    constexpr int SMEM = (32 * AS * 2 > 32 * 128 * 4) ? 32 * AS * 2 : 32 * 128 * 4;
    __shared__ __align__(16) char smem[SMEM];     // Asm; aliased by Hs post-MFMA (POOL)
    unsigned short* Asm = (unsigned short*)smem;
    float* Hs = (float*)smem;
    __shared__ __align__(16) float sP[32 * 4];
    __shared__ __align__(16) float qP[32 * 4];
    __shared__ int bS[POOL ? 32 : 1];

    const int tid = threadIdx.x;
    const int n0 = blockIdx.x * 32;

    if (POOL && tid < 32) {
        int gn = n0 + tid;
        bS[tid] = (gn < NN) ? batch[gn] : -1;
    }
    // stage A tile: first CPRh chunks from Ag, rest from Hr
    for (int i = tid; i < 32 * CPR; i += 256) {
        int node = i / CPR, c = i - node * CPR;
        size_t gn = (size_t)(n0 + node);
        const unsigned short* src = (c < CPRh)
            ? (Ag + gn * KH + c * 8)
            : (Hr + gn * KH + (c - CPRh) * 8);
        uint4 v = *(const uint4*)src;
        *(uint4*)(Asm + node * AS + c * 8) = v;
    }

    const int l = tid & 63, w = tid >> 6;
    const int g = l >> 4, c0 = l & 15;
    float bia[2], gam[2], bet[2];
    #pragma unroll
    for (int j = 0; j < 2; ++j) {
        int col = (2 * w + j) * 16 + c0;
        bia[j] = bias[col]; gam[j] = gamma[col]; bet[j] = beta[col];
    }
    const unsigned short* bp0 = Wt + (size_t)((2 * w + 0) * 16 + c0) * K + g * 8;
    const unsigned short* bp1 = Wt + (size_t)((2 * w + 1) * 16 + c0) * K + g * 8;
    const unsigned short* ar0 = Asm + (0 * 16 + c0) * AS + g * 8;
    const unsigned short* ar1 = Asm + (1 * 16 + c0) * AS + g * 8;
    __syncthreads();

    f32x4 acc[2][2];
    acc[0][0] = (f32x4){0.f,0.f,0.f,0.f}; acc[0][1] = (f32x4){0.f,0.f,0.f,0.f};
    acc[1][0] = (f32x4){0.f,0.f,0.f,0.f}; acc[1][1] = (f32x4){0.f,0.f,0.f,0.f};

    #pragma unroll
    for (int kt = 0; kt < KT; ++kt) {
        bf16x8 b0 = *(const bf16x8*)(bp0 + kt * 32);
        bf16x8 b1 = *(const bf16x8*)(bp1 + kt * 32);
        bf16x8 a0 = *(const bf16x8*)(ar0 + kt * 32);
        bf16x8 a1 = *(const bf16x8*)(ar1 + kt * 32);
        acc[0][0] = __builtin_amdgcn_mfma_f32_16x16x32_bf16(a0, b0, acc[0][0], 0, 0, 0);
        acc[0][1] = __builtin_amdgcn_mfma_f32_16x16x32_bf16(a0, b1, acc[0][1], 0, 0, 0);
        acc[1][0] = __builtin_amdgcn_mfma_f32_16x16x32_bf16(a1, b0, acc[1][0], 0, 0, 0);
        acc[1][1] = __builtin_amdgcn_mfma_f32_16x16x32_bf16(a1, b1, acc[1][1], 0, 0, 0);
    }

    // LN phase 1: per-wave partials over this wave's 32 cols
    #pragma unroll
    for (int m = 0; m < 2; ++m) {
        #pragma unroll
        for (int r = 0; r < 4; ++r) {
            float h0v = acc[m][0][r] + bia[0];
            float h1v = acc[m][1][r] + bia[1];
            float s = h0v + h1v, q = h0v * h0v + h1v * h1v;
            #pragma unroll
            for (int mm = 1; mm < 16; mm <<= 1) {
                s += __shfl_xor(s, mm, 64);
                q += __shfl_xor(q, mm, 64);
            }
            if (c0 == 0) {
                int node = m * 16 + g * 4 + r;
                sP[node * 4 + w] = s;
                qP[node * 4 + w] = q;
            }
        }
    }
    __syncthreads();   // MFMA Asm reads done; sP/qP visible

    // LN phase 2 + ReLU + store
    #pragma unroll
    for (int m = 0; m < 2; ++m) {
        #pragma unroll
        for (int r = 0; r < 4; ++r) {
            int node = m * 16 + g * 4 + r;
            float4 sv = *(const float4*)&sP[node * 4];
            float4 qv = *(const float4*)&qP[node * 4];
            float s = (sv.x + sv.y) + (sv.z + sv.w);
            float q = (qv.x + qv.y) + (qv.z + qv.w);
            float mu   = s * (1.f / 128.f);
            float var  = q * (1.f / 128.f) - mu * mu;
            float rinv = rsqrtf(var + LN_EPS);
            float h0v = acc[m][0][r] + bia[0];
            float h1v = acc[m][1][r] + bia[1];
            float v0 = fmaxf(0.f, (h0v - mu) * rinv * gam[0] + bet[0]);
            float v1 = fmaxf(0.f, (h1v - mu) * rinv * gam[1] + bet[1]);
            if (POOL) {
                Hs[node * 128 + (2 * w) * 16 + c0]     = v0;
                Hs[node * 128 + (2 * w + 1) * 16 + c0] = v1;
            } else {
                size_t gn = (size_t)(n0 + node);
                outH[gn * 128 + (2 * w) * 16 + c0]     = f2bf(v0);
                outH[gn * 128 + (2 * w + 1) * 16 + c0] = f2bf(v1);
            }
        }
    }
    if (!POOL) return;
    __syncthreads();

    // fused pooling: 128 threads, one column each; sorted batch -> few flushes
    if (tid < 128) {
        int j = tid;
        int curg = -1; float s = 0.f, m = 0.f;
        #pragma unroll 4
        for (int n = 0; n < 32; ++n) {
            int gb = bS[n];
            if (gb < 0) break;
            if (gb != curg) {
                if (curg >= 0) {
                    atomicAdd(&psum[curg * 128 + j], s);
                    atomicMax(&pmax[curg * 128 + j], __float_as_int(m));
                }
                curg = gb; s = 0.f; m = 0.f;
            }
            float v = Hs[n * 128 + j];
            s += v; m = fmaxf(m, v);
        }
        if (curg >= 0) {
            atomicAdd(&psum[curg * 128 + j], s);
            atomicMax(&pmax[curg * 128 + j], __float_as_int(m));
        }
    }
}

// ---------------- final MLP (one block per graph; cnt via binary search) ----------------
__device__ __forceinline__ int lbound(const int* a, int n, int v) {
    int lo = 0, hi = n;
    while (lo < hi) { int mid = (lo + hi) >> 1; if (a[mid] < v) lo = mid + 1; else hi = mid; }
    return lo;
}

__global__ __launch_bounds__(64) void mlp_kernel(
    const float* __restrict__ psum, const int* __restrict__ pmax,
    const int* __restrict__ batch,
    const float* __restrict__ Wf0, const float* __restrict__ bf0,
    const float* __restrict__ Wf1, const float* __restrict__ bf1,
    const float* __restrict__ Wf2, const float* __restrict__ bf2,
    float* __restrict__ out)
{
    __shared__ float z[256];
    __shared__ float t1[50];
    __shared__ float t2[50];
    __shared__ int cS;
    int g = blockIdx.x, t = threadIdx.x;
    if (t == 0) cS = lbound(batch, NN, g + 1) - lbound(batch, NN, g);
    __syncthreads();
    int c = cS;
    float ic = 1.0f / (float)(c > 1 ? c : 1);
    for (int j = t; j < 128; j += 64) {
        z[j]       = psum[g * 128 + j] * ic;
        z[128 + j] = __int_as_float(pmax[g * 128 + j]);
    }
    __syncthreads();
    if (t < 50) {
        float a = bf0[t];
        for (int k = 0; k < 256; ++k) a = fmaf(z[k], Wf0[k * 50 + t], a);
        t1[t] = fmaxf(a, 0.0f);
    }
    __syncthreads();
    if (t < 50) {
        float a = bf1[t];
        for (int k = 0; k < 50; ++k) a = fmaf(t1[k], Wf1[k * 50 + t], a);
        t2[t] = fmaxf(a, 0.0f);
    }
    __syncthreads();
    if (t < 10) {
        float a = bf2[t];
        for (int k = 0; k < 50; ++k) a = fmaf(t2[k], Wf2[k * 10 + t], a);
        out[g * 10 + t] = fmaxf(a, 0.0f);
    }
}

// ---------------- launcher ----------------
extern "C" void kernel_launch(void* const* d_in, const int* in_sizes, int n_in,
                              void* d_out, int out_size, void* d_ws, size_t ws_size,
                              hipStream_t stream)
{
    const float* x     = (const float*)d_in[0];
    const float* xdims = (const float*)d_in[1];
    const int*   stt   = (const int*)d_in[2];
    const int*   ei    = (const int*)d_in[3];
    const int*   batch = (const int*)d_in[4];
    const float* emb   = (const float*)d_in[5];
    const float* Wl0   = (const float*)d_in[6];
    const float* bl0   = (const float*)d_in[7];
    const float* Wr0   = (const float*)d_in[8];
    const float* g0    = (const float*)d_in[9];
    const float* bn0   = (const float*)d_in[10];
    const float* Wl1   = (const float*)d_in[11];
    const float* bl1   = (const float*)d_in[12];
    const float* Wr1   = (const float*)d_in[13];
    const float* g1    = (const float*)d_in[14];
    const float* bn1   = (const float*)d_in[15];
    const float* Wf0   = (const float*)d_in[16];
    const float* bf0   = (const float*)d_in[17];
    const float* Wf1   = (const float*)d_in[18];
    const float* bf1   = (const float*)d_in[19];
    const float* Wf2   = (const float*)d_in[20];
    const float* bf2   = (const float*)d_in[21];

    char* w = (char*)d_ws;
    unsigned short* H0r = (unsigned short*)w; w += (size_t)NP * 80 * 2;
    unsigned short* A0g = (unsigned short*)w; w += (size_t)NP * 80 * 2;
    unsigned short* H1  = (unsigned short*)w; w += (size_t)NP * 128 * 2;
    unsigned short* A1g = (unsigned short*)w; w += (size_t)NP * 128 * 2;
    unsigned short* Wt0 = (unsigned short*)w; w += (size_t)128 * 160 * 2;
    unsigned short* Wt1 = (unsigned short*)w; w += (size_t)128 * 256 * 2;
    int*   csr    = (int*)w;   w += (size_t)EE * 4;
    int*   offs   = (int*)w;   w += (size_t)NN * 4;
    int*   bsum   = (int*)w;   w += 1024;
    // zeroed region (one memset):
    char* zbeg = w;
    int*   deg  = (int*)w;   w += (size_t)NP * 4;
    int*   cur  = (int*)w;   w += (size_t)NN * 4;
    float* psum = (float*)w; w += (size_t)GG * 128 * 4;
    int*   pmax = (int*)w;   w += (size_t)GG * 128 * 4;
    size_t zsz = (size_t)(w - zbeg);

    hipMemsetAsync(zbeg, 0, zsz, stream);

    prep_kernel<<<(PREP_TOT + 255) / 256, 256, 0, stream>>>(
        x, xdims, stt, emb, ei, Wl0, Wr0, Wl1, Wr1, H0r, Wt0, Wt1, deg);

    int nb = (NN + 2047) / 2048;   // 49
    scan1_kernel<<<nb, 256, 0, stream>>>(deg, offs, bsum);
    scan2_kernel<<<1, 64, 0, stream>>>(bsum, nb);
    fill_csr_kernel<<<(EE + 255) / 256, 256, 0, stream>>>(ei, cur, offs, bsum, csr);

    agg0_kernel<<<NP / 16, 256, 0, stream>>>(H0r, A0g, csr, offs, bsum, deg);
    gemm_kernel<160, false><<<NT, 256, 0, stream>>>(
        A0g, H0r, Wt0, bl0, g0, bn0, H1, nullptr, nullptr, nullptr);
    agg1_kernel<<<NP / 16, 256, 0, stream>>>(H1, A1g, csr, offs, bsum, deg);
    gemm_kernel<256, true><<<NT, 256, 0, stream>>>(
        A1g, H1, Wt1, bl1, g1, bn1, nullptr, batch, psum, pmax);

    mlp_kernel<<<GG, 64, 0, stream>>>(psum, pmax, batch, Wf0, bf0, Wf1, bf1, Wf2, bf2,
                                      (float*)d_out);
}